// Round 1
// baseline (5956.029 us; speedup 1.0000x reference)
//
#include <hip/hip_runtime.h>
#include <cstddef>
#include <cstdint>

// Problem constants
#define TT 256
#define BB 64
#define NTAG 34
// M = TT*BB = 16384

__device__ __forceinline__ float sigf(float x) { return 1.0f / (1.0f + expf(-x)); }

// ---------------------------------------------------------------------------
// Transpose w_hh (2,1024,256) -> WT (2,256,1024) so the recurrence reads
// W^T[k][g] coalesced (consecutive g across lanes).
// ---------------------------------------------------------------------------
__global__ __launch_bounds__(256) void transpose_whh(const float* __restrict__ w,
                                                     float* __restrict__ wt) {
  __shared__ float tile[32][33];
  int d = blockIdx.z;
  int g0 = blockIdx.x * 32;
  int k0 = blockIdx.y * 32;
  int lx = threadIdx.x;   // 0..31
  int ly = threadIdx.y;   // 0..7
  for (int i = ly; i < 32; i += 8)
    tile[i][lx] = w[((size_t)d * 1024 + g0 + i) * 256 + k0 + lx];
  __syncthreads();
  for (int i = ly; i < 32; i += 8)
    wt[((size_t)d * 256 + k0 + i) * 1024 + g0 + lx] = tile[lx][i];
}

// ---------------------------------------------------------------------------
// fp32 tiled GEMM: out[m][n] = sum_k A[m][k] * W[n][k] + biasA[n] (+ biasB[n])
// A row source: direct (m*K) or gathered (gidx[m]*K) for the embedding lookup.
// xp_mode=1: store to xp[dir][m][1024] layout (dir = n>>10). else ld=Nvalid.
// BM=BN=64, BK=32, 256 threads, 4x4 micro-tile.
// ---------------------------------------------------------------------------
__global__ __launch_bounds__(256) void gemm_k(
    const float* __restrict__ Abase, const int* __restrict__ gidx,
    const float* __restrict__ W, const float* __restrict__ biasA,
    const float* __restrict__ biasB, float* __restrict__ out,
    int M, int K, int Nvalid, int xp_mode) {
  __shared__ float As[32][68];  // [k][m], +4 pad keeps float4 alignment
  __shared__ float Bs[32][68];  // [k][n]
  int tid = threadIdx.x;
  int m0 = blockIdx.x * 64;
  int n0 = blockIdx.y * 64;
  int tx = tid & 15, ty = tid >> 4;
  int lk = (tid & 7) * 4;  // k offset 0..28
  int lr = tid >> 3;       // row 0..31 (and +32)

  float acc[4][4] = {};

  const float* arow0;
  const float* arow1;
  {
    int ma = m0 + lr, mb = m0 + lr + 32;
    size_t ra = gidx ? (size_t)gidx[ma] : (size_t)ma;
    size_t rb = gidx ? (size_t)gidx[mb] : (size_t)mb;
    arow0 = Abase + ra * (size_t)K;
    arow1 = Abase + rb * (size_t)K;
  }
  int nA = n0 + lr, nB = n0 + lr + 32;
  const float* wr0 = W + (size_t)nA * K;
  const float* wr1 = W + (size_t)nB * K;
  bool v0 = nA < Nvalid, v1 = nB < Nvalid;

  for (int k0 = 0; k0 < K; k0 += 32) {
    float4 a0 = *(const float4*)(arow0 + k0 + lk);
    float4 a1 = *(const float4*)(arow1 + k0 + lk);
    float4 b0 = v0 ? *(const float4*)(wr0 + k0 + lk) : make_float4(0, 0, 0, 0);
    float4 b1 = v1 ? *(const float4*)(wr1 + k0 + lk) : make_float4(0, 0, 0, 0);
    __syncthreads();  // previous iteration's compute done before overwrite
    As[lk + 0][lr] = a0.x; As[lk + 1][lr] = a0.y; As[lk + 2][lr] = a0.z; As[lk + 3][lr] = a0.w;
    As[lk + 0][lr + 32] = a1.x; As[lk + 1][lr + 32] = a1.y; As[lk + 2][lr + 32] = a1.z; As[lk + 3][lr + 32] = a1.w;
    Bs[lk + 0][lr] = b0.x; Bs[lk + 1][lr] = b0.y; Bs[lk + 2][lr] = b0.z; Bs[lk + 3][lr] = b0.w;
    Bs[lk + 0][lr + 32] = b1.x; Bs[lk + 1][lr + 32] = b1.y; Bs[lk + 2][lr + 32] = b1.z; Bs[lk + 3][lr + 32] = b1.w;
    __syncthreads();
#pragma unroll
    for (int k = 0; k < 32; ++k) {
      float4 av = *(const float4*)&As[k][ty * 4];
      float4 bv = *(const float4*)&Bs[k][tx * 4];
#pragma unroll
      for (int i = 0; i < 4; ++i) {
        float a = (&av.x)[i];
        acc[i][0] += a * bv.x;
        acc[i][1] += a * bv.y;
        acc[i][2] += a * bv.z;
        acc[i][3] += a * bv.w;
      }
    }
  }
#pragma unroll
  for (int i = 0; i < 4; ++i) {
    int m = m0 + ty * 4 + i;
#pragma unroll
    for (int j = 0; j < 4; ++j) {
      int n = n0 + tx * 4 + j;
      if (n < Nvalid) {
        float v = acc[i][j] + biasA[n] + (biasB ? biasB[n] : 0.0f);
        if (xp_mode)
          out[((size_t)(n >> 10) * M + m) * 1024 + (n & 1023)] = v;
        else
          out[(size_t)m * Nvalid + n] = v;
      }
    }
  }
}

// ---------------------------------------------------------------------------
// LSTM recurrence, one direction-batch-pair per block.
// grid = 64: blocks 0..31 -> dir 0 (fwd), 32..63 -> dir 1 (bwd); each block
// owns batches (2*bp, 2*bp+1). 256 threads; thread g4=4*tid accumulates 4
// consecutive gate rows for both batch elements. W^T streamed from L2 as
// float4, double-buffered 16-deep to keep ~16 KB/wave in flight.
// out[t*B+b][dir*256 + j] = masked hidden output.
// ---------------------------------------------------------------------------
__global__ __launch_bounds__(256, 1) void lstm_rec(
    const float* __restrict__ xp,   // [2][M][1024]
    const float* __restrict__ WT,   // [2][256][1024]
    const int* __restrict__ lengths,
    float* __restrict__ out,        // [M][512]
    int T, int B) {
  __shared__ float hS[2][256];
  __shared__ float cS[2][256];
  __shared__ float gS[2][1024];
  int blk = blockIdx.x;
  int d = blk >> 5;
  int bp = blk & 31;
  int b0 = bp * 2;
  int tid = threadIdx.x;
  hS[0][tid] = 0.0f; hS[1][tid] = 0.0f;
  cS[0][tid] = 0.0f; cS[1][tid] = 0.0f;
  int len0 = lengths[b0], len1 = lengths[b0 + 1];
  const float* wbase = WT + (size_t)d * 256 * 1024 + tid * 4;
  size_t M = (size_t)T * B;
  __syncthreads();

  float4 wa[16], wb[16];
  for (int s = 0; s < T; ++s) {
    int t = d ? (T - 1 - s) : s;
    const float* xr = xp + ((size_t)d * M + (size_t)t * B + b0) * 1024 + tid * 4;
    float4 acc0 = *(const float4*)(xr);
    float4 acc1 = *(const float4*)(xr + 1024);
#pragma unroll
    for (int u = 0; u < 16; ++u) wa[u] = *(const float4*)(wbase + (size_t)u * 1024);
    for (int kc = 0; kc < 256; kc += 32) {
      const float* p1 = wbase + (size_t)(kc + 16) * 1024;
#pragma unroll
      for (int u = 0; u < 16; ++u) wb[u] = *(const float4*)(p1 + (size_t)u * 1024);
#pragma unroll
      for (int q = 0; q < 4; ++q) {
        float4 h0v = *(const float4*)&hS[0][kc + q * 4];
        float4 h1v = *(const float4*)&hS[1][kc + q * 4];
#pragma unroll
        for (int u = 0; u < 4; ++u) {
          float4 w = wa[q * 4 + u];
          float ha = (&h0v.x)[u];
          float hb = (&h1v.x)[u];
          acc0.x += w.x * ha; acc0.y += w.y * ha; acc0.z += w.z * ha; acc0.w += w.w * ha;
          acc1.x += w.x * hb; acc1.y += w.y * hb; acc1.z += w.z * hb; acc1.w += w.w * hb;
        }
      }
      if (kc + 32 < 256) {
        const float* p2 = wbase + (size_t)(kc + 32) * 1024;
#pragma unroll
        for (int u = 0; u < 16; ++u) wa[u] = *(const float4*)(p2 + (size_t)u * 1024);
      }
#pragma unroll
      for (int q = 0; q < 4; ++q) {
        float4 h0v = *(const float4*)&hS[0][kc + 16 + q * 4];
        float4 h1v = *(const float4*)&hS[1][kc + 16 + q * 4];
#pragma unroll
        for (int u = 0; u < 4; ++u) {
          float4 w = wb[q * 4 + u];
          float ha = (&h0v.x)[u];
          float hb = (&h1v.x)[u];
          acc0.x += w.x * ha; acc0.y += w.y * ha; acc0.z += w.z * ha; acc0.w += w.w * ha;
          acc1.x += w.x * hb; acc1.y += w.y * hb; acc1.z += w.z * hb; acc1.w += w.w * hb;
        }
      }
    }
    *(float4*)&gS[0][tid * 4] = acc0;
    *(float4*)&gS[1][tid * 4] = acc1;
    __syncthreads();
    // pointwise gates -> state update; j = tid owns hidden unit j
    int j = tid;
#pragma unroll
    for (int e = 0; e < 2; ++e) {
      float ii = sigf(gS[e][j]);
      float ff = sigf(gS[e][256 + j]);
      float gg = tanhf(gS[e][512 + j]);
      float oo = sigf(gS[e][768 + j]);
      float cn = ff * cS[e][j] + ii * gg;
      float hn = oo * tanhf(cn);
      bool m = t < (e ? len1 : len0);
      float hu = m ? hn : hS[e][j];
      float cu = m ? cn : cS[e][j];
      hS[e][j] = hu;
      cS[e][j] = cu;
      out[((size_t)t * B + (b0 + e)) * 512 + d * 256 + j] = m ? hu : 0.0f;
    }
    __syncthreads();
  }
}

// ---------------------------------------------------------------------------
// Viterbi: one block (one wave) per batch element. Forward max-sum with
// first-occurrence argmax (strict >, i ascending = jnp.argmax semantics),
// masked steps keep score and store identity backpointers. Lane 0 backtracks.
// ---------------------------------------------------------------------------
__global__ __launch_bounds__(64) void viterbi_k(
    const float* __restrict__ em, const int* __restrict__ lengths,
    const float* __restrict__ startT, const float* __restrict__ endT,
    const float* __restrict__ trans, int* __restrict__ hist,
    int* __restrict__ outTags, int T, int B) {
  __shared__ float tr[NTAG * NTAG];
  __shared__ float sc[NTAG];
  __shared__ float ns[NTAG];
  int b = blockIdx.x;
  int j = threadIdx.x;
  for (int i = j; i < NTAG * NTAG; i += 64) tr[i] = trans[i];
  int len = lengths[b];
  if (j < NTAG) sc[j] = startT[j] + em[(size_t)b * NTAG + j];
  __syncthreads();
  for (int t = 1; t < T; ++t) {
    if (j < NTAG) {
      float best = -3.0e38f;
      int arg = 0;
      for (int i = 0; i < NTAG; ++i) {
        float v = sc[i] + tr[i * NTAG + j];
        if (v > best) { best = v; arg = i; }
      }
      bool m = t < len;
      float e = em[((size_t)t * B + b) * NTAG + j];
      ns[j] = m ? (best + e) : sc[j];
      hist[((size_t)(t - 1) * B + b) * NTAG + j] = m ? arg : j;
    }
    __syncthreads();
    if (j < NTAG) sc[j] = ns[j];
    __syncthreads();
  }
  if (j == 0) {
    float best = -3.0e38f;
    int arg = 0;
    for (int i = 0; i < NTAG; ++i) {
      float v = sc[i] + endT[i];
      if (v > best) { best = v; arg = i; }
    }
    int tag = arg;
    outTags[(size_t)(T - 1) * B + b] = (T - 1 < len) ? tag : 0;
    for (int t = T - 2; t >= 0; --t) {
      tag = hist[((size_t)t * B + b) * NTAG + tag];
      outTags[(size_t)t * B + b] = (t < len) ? tag : 0;
    }
  }
}

extern "C" void kernel_launch(void* const* d_in, const int* in_sizes, int n_in,
                              void* d_out, int out_size, void* d_ws, size_t ws_size,
                              hipStream_t stream) {
  const int* x = (const int*)d_in[0];            // (T,B) int32
  const int* lens = (const int*)d_in[1];         // (B,)
  const float* embed = (const float*)d_in[2];    // (VOCAB,256)
  const float* w_ih0 = (const float*)d_in[3];    // (2,1024,256)
  const float* w_hh0 = (const float*)d_in[4];    // (2,1024,256)
  const float* b_ih0 = (const float*)d_in[5];    // (2,1024)
  const float* b_hh0 = (const float*)d_in[6];
  const float* w_ih1 = (const float*)d_in[7];    // (2,1024,512)
  const float* w_hh1 = (const float*)d_in[8];    // (2,1024,256)
  const float* b_ih1 = (const float*)d_in[9];
  const float* b_hh1 = (const float*)d_in[10];
  const float* w_lin = (const float*)d_in[11];   // (34,512)
  const float* b_lin = (const float*)d_in[12];   // (34,)
  const float* startT = (const float*)d_in[13];
  const float* endT = (const float*)d_in[14];
  const float* trans = (const float*)d_in[15];   // (34,34)
  int* outTags = (int*)d_out;                    // (T,B) int32

  const int T = TT, B = BB;
  const int M = T * B;  // 16384

  // Workspace layout (~204.2 MiB total)
  char* ws = (char*)d_ws;
  const size_t SZ_XP = 2ull * M * 1024 * 4;    // 134217728
  const size_t SZ_H = (size_t)M * 512 * 4;     // 33554432
  const size_t SZ_EM = (size_t)M * NTAG * 4;   // 2228224
  const size_t SZ_HIST = (size_t)M * NTAG * 4; // 2228224 (only T-1 slices used)
  float* xp = (float*)(ws);
  float* h0 = (float*)(ws + SZ_XP);
  float* h1 = (float*)(ws + SZ_XP + SZ_H);
  float* em = (float*)(ws + SZ_XP + 2 * SZ_H);
  int* hist = (int*)(ws + SZ_XP + 2 * SZ_H + SZ_EM);
  float* wt0 = (float*)(ws + SZ_XP + 2 * SZ_H + SZ_EM + SZ_HIST);
  float* wt1 = wt0 + 2 * 256 * 1024;

  // 1. Transpose recurrent weights (per layer)
  transpose_whh<<<dim3(32, 8, 2), dim3(32, 8), 0, stream>>>(w_hh0, wt0);
  transpose_whh<<<dim3(32, 8, 2), dim3(32, 8), 0, stream>>>(w_hh1, wt1);

  // 2. Layer-0 input projection (fused embedding gather): xp[dir][m][1024]
  gemm_k<<<dim3(M / 64, 32), 256, 0, stream>>>(embed, x, w_ih0, b_ih0, b_hh0,
                                               xp, M, 256, 2048, 1);
  // 3. Layer-0 recurrence -> h0[m][512]
  lstm_rec<<<64, 256, 0, stream>>>(xp, wt0, lens, h0, T, B);

  // 4. Layer-1 input projection
  gemm_k<<<dim3(M / 64, 32), 256, 0, stream>>>(h0, nullptr, w_ih1, b_ih1, b_hh1,
                                               xp, M, 512, 2048, 1);
  // 5. Layer-1 recurrence -> h1[m][512]
  lstm_rec<<<64, 256, 0, stream>>>(xp, wt1, lens, h1, T, B);

  // 6. Emissions: em[m][34]
  gemm_k<<<dim3(M / 64, 1), 256, 0, stream>>>(h1, nullptr, w_lin, b_lin, nullptr,
                                              em, M, 512, 34, 0);
  // 7. Viterbi decode -> outTags
  viterbi_k<<<64, 64, 0, stream>>>(em, lens, startT, endT, trans, hist, outTags,
                                   T, B);
  (void)in_sizes; (void)n_in; (void)out_size; (void)ws_size;
}